// Round 1
// 1585.419 us; speedup vs baseline: 2.0336x; 2.0336x over previous
//
#include <hip/hip_runtime.h>
#include <hip/hip_bf16.h>
#include <cstdint>

// Problem dims (B=1)
#define L_SEQ 2048
#define NH    24
#define DH    128
#define HID   3072          // NH*DH
#define MLPD  12288         // 4*HID
#define N1    21504         // 3*HID + MLP
#define K2    15360         // HID + MLP
#define EPSF  1e-6f
#define ATT_SCALE 0.08838834764831845f

typedef __bf16 bf16x8 __attribute__((ext_vector_type(8)));
typedef float  f32x4  __attribute__((ext_vector_type(4)));

__device__ __forceinline__ float gelu_tanh(float x) {
    float x3 = x * x * x;
    return 0.5f * x * (1.f + tanhf(0.7978845608028654f * (x + 0.044715f * x3)));
}

// float -> bf16 bits, round-to-nearest-even (finite inputs)
__device__ __forceinline__ unsigned short f2bf(float f) {
    union { float f; unsigned int u; } x{f};
    unsigned int r = x.u + 0x7fffu + ((x.u >> 16) & 1u);
    return (unsigned short)(r >> 16);
}

// async global->LDS, 16B per lane; LDS dest is wave-uniform base + lane*16
__device__ __forceinline__ void gload_lds16(const void* g, void* l) {
    __builtin_amdgcn_global_load_lds(
        (__attribute__((address_space(1))) void*)g,
        (__attribute__((address_space(3))) void*)l, 16, 0, 0);
}

// ---------------- fp32 [R][C] -> bf16 [C][R] tile transpose ---------------
__global__ __launch_bounds__(256)
void k_convT(const float* __restrict__ in, unsigned short* __restrict__ out,
             int R, int C) {
    __shared__ unsigned short s[64][72];
    const int r0 = blockIdx.y * 64, c0 = blockIdx.x * 64;
    const int tid = threadIdx.x;
    const int row = tid >> 4, c4 = (tid & 15) * 4;
    #pragma unroll
    for (int rr = 0; rr < 4; rr++) {
        int r = row + rr * 16;
        float4 v = *(const float4*)&in[(size_t)(r0 + r) * C + c0 + c4];
        s[r][c4 + 0] = f2bf(v.x); s[r][c4 + 1] = f2bf(v.y);
        s[r][c4 + 2] = f2bf(v.z); s[r][c4 + 3] = f2bf(v.w);
    }
    __syncthreads();
    #pragma unroll
    for (int rr = 0; rr < 4; rr++) {
        int oc = row + rr * 16;          // tile-col index (out row)
        ushort4 t = make_ushort4(s[c4 + 0][oc], s[c4 + 1][oc],
                                 s[c4 + 2][oc], s[c4 + 3][oc]);
        *(ushort4*)&out[(size_t)(c0 + oc) * R + r0 + c4] = t;
    }
}

// ---------------- mod = silu(vec) @ mod_w + mod_b  (split-K + atomics) -----
__global__ __launch_bounds__(256)
void k_mod(const float* __restrict__ vec, const float* __restrict__ mod_w,
           const float* __restrict__ mod_b, float* __restrict__ mod) {
    __shared__ float sv[384];
    const int j  = blockIdx.x * 256 + threadIdx.x;   // 0..9215
    const int k0 = blockIdx.y * 384;
    for (int i = threadIdx.x; i < 384; i += 256) {
        float v = vec[k0 + i];
        sv[i] = v / (1.f + __expf(-v));
    }
    __syncthreads();
    float acc = (blockIdx.y == 0) ? mod_b[j] : 0.f;
    #pragma unroll 8
    for (int i = 0; i < 384; i++)
        acc = fmaf(sv[i], mod_w[(size_t)(k0 + i) * 9216 + j], acc);
    atomicAdd(&mod[j], acc);
}

// ---------------- LayerNorm + modulate -> bf16 ----------------------------
__global__ __launch_bounds__(256)
void k_ln(const float* __restrict__ x, const float* __restrict__ mod,
          const float* __restrict__ gamma, const float* __restrict__ beta,
          unsigned short* __restrict__ x_mod) {
    __shared__ float rs_[4], rs2_[4];
    const int l = blockIdx.x, tid = threadIdx.x;
    const float* xr = x + (size_t)l * HID;
    float s = 0.f, s2 = 0.f;
    for (int i = tid; i < HID; i += 256) {
        float v = xr[i]; s += v; s2 = fmaf(v, v, s2);
    }
    #pragma unroll
    for (int off = 32; off; off >>= 1) { s += __shfl_xor(s, off); s2 += __shfl_xor(s2, off); }
    const int w = tid >> 6;
    if ((tid & 63) == 0) { rs_[w] = s; rs2_[w] = s2; }
    __syncthreads();
    s  = rs_[0] + rs_[1] + rs_[2] + rs_[3];
    s2 = rs2_[0] + rs2_[1] + rs2_[2] + rs2_[3];
    float mu   = s * (1.f / HID);
    float var  = s2 * (1.f / HID) - mu * mu;
    float rstd = rsqrtf(var + EPSF);
    unsigned short* orow = x_mod + (size_t)l * HID;
    for (int i = tid; i < HID; i += 256) {
        float ln = (xr[i] - mu) * rstd * gamma[i] + beta[i];
        orow[i] = f2bf(fmaf(1.f + mod[HID + i], ln, mod[i]));
    }
}

// ---------------- bf16 MFMA GEMM (B^T input), 128x128x32 ------------------
// MODE 0: x_mod[2048][3072] @ w1t^T -> q,k scatter (fp32) + v -> bf16 [h][d][l]
//         + gelu(mlp)->a2 bf16
// MODE 1: a2[2048][15360] @ w2t^T  -> out = x + gate*val (fp32)
template<int MODE>
__global__ __launch_bounds__(256)
void gemm_bt(const unsigned short* __restrict__ A,
             const unsigned short* __restrict__ Bt,
             const float* __restrict__ bias, int K,
             float* __restrict__ qkv, unsigned short* __restrict__ vt,
             unsigned short* __restrict__ a2,
             const float* __restrict__ xres, const float* __restrict__ mod,
             float* __restrict__ out) {
    __shared__ unsigned short As[128 * 32];
    __shared__ unsigned short Bs[128 * 32];
    const int tid = threadIdx.x;
    const int bm = blockIdx.y * 128, bn = blockIdx.x * 128;
    const int w = tid >> 6, lane = tid & 63;
    const int wm = w >> 1, wn = w & 1;
    const int quad = lane >> 4, lr = lane & 15;
    const int srow = lane >> 2, spart = lane & 3;   // staging: 4 lanes/row x 16B

    f32x4 acc[4][4] = {};

    for (int k0 = 0; k0 < K; k0 += 32) {
        #pragma unroll
        for (int s = 0; s < 2; s++) {
            const int slot = w + s * 4;             // 16 rows per slot
            gload_lds16(&A [(size_t)(bm + slot * 16 + srow) * K + k0 + spart * 8],
                        &As[slot * 512]);
            gload_lds16(&Bt[(size_t)(bn + slot * 16 + srow) * K + k0 + spart * 8],
                        &Bs[slot * 512]);
        }
        __syncthreads();
        bf16x8 af[4], bfr[4];
        #pragma unroll
        for (int t = 0; t < 4; t++) {
            af[t]  = *(const bf16x8*)&As[(wm * 64 + t * 16 + lr) * 32 + quad * 8];
            bfr[t] = *(const bf16x8*)&Bs[(wn * 64 + t * 16 + lr) * 32 + quad * 8];
        }
        #pragma unroll
        for (int mt = 0; mt < 4; mt++)
            #pragma unroll
            for (int nt = 0; nt < 4; nt++)
                acc[mt][nt] = __builtin_amdgcn_mfma_f32_16x16x32_bf16(
                    af[mt], bfr[nt], acc[mt][nt], 0, 0, 0);
        __syncthreads();
    }

    #pragma unroll
    for (int mt = 0; mt < 4; mt++) {
        #pragma unroll
        for (int nt = 0; nt < 4; nt++) {
            const int col = bn + wn * 64 + nt * 16 + lr;
            const float bs = bias[col];
            #pragma unroll
            for (int r = 0; r < 4; r++) {
                const int row = bm + wm * 64 + mt * 16 + quad * 4 + r;
                float v = acc[mt][nt][r] + bs;
                if (MODE == 0) {
                    if (col < 2 * HID) {
                        int s3 = col / HID, rem = col - s3 * HID;
                        int hh = rem >> 7, d = rem & 127;
                        qkv[(((size_t)s3 * NH + hh) * L_SEQ + row) * DH + d] = v;
                    } else if (col < 3 * HID) {
                        int rem = col - 2 * HID;
                        int hh = rem >> 7, d = rem & 127;
                        vt[((size_t)hh * DH + d) * L_SEQ + row] = f2bf(v);
                    } else {
                        a2[(size_t)row * K2 + col - 6144] = f2bf(gelu_tanh(v));
                    }
                } else {
                    out[(size_t)row * HID + col] =
                        fmaf(mod[2 * HID + col], v, xres[(size_t)row * HID + col]);
                }
            }
        }
    }
}

// ---------------- RMSNorm(q,k) + RoPE  (fp32 in, bf16 out) ----------------
// q additionally pre-scaled by 1/sqrt(D) so attn QK^T needs no scale.
__global__ __launch_bounds__(64)
void k_rmsrope(const float* __restrict__ qkv, const float* __restrict__ pe,
               const float* __restrict__ qsc, const float* __restrict__ ksc,
               unsigned short* __restrict__ qb, unsigned short* __restrict__ kb) {
    const int idx = blockIdx.x;            // h*L + l
    const int h = idx >> 11, l = idx & 2047;
    const int p = threadIdx.x;             // pair index 0..63
    const float* qp = qkv + ((size_t)h * L_SEQ + l) * DH;
    const float* kp = qkv + ((size_t)(NH + h) * L_SEQ + l) * DH;
    const float4 pv = *(const float4*)&pe[((size_t)l * 64 + p) * 4];
    const float2 qs2 = *(const float2*)&qsc[2 * p];
    const float2 ks2 = *(const float2*)&ksc[2 * p];

    float2 t = *(const float2*)&qp[2 * p];
    float ss = fmaf(t.x, t.x, t.y * t.y);
    #pragma unroll
    for (int off = 32; off; off >>= 1) ss += __shfl_xor(ss, off);
    float r = rsqrtf(ss * (1.f / DH) + EPSF);
    float a = t.x * r * qs2.x, b = t.y * r * qs2.y;
    *(ushort2*)&qb[((size_t)h * L_SEQ + l) * DH + 2 * p] =
        make_ushort2(f2bf(fmaf(pv.x, a, pv.y * b) * ATT_SCALE),
                     f2bf(fmaf(pv.z, a, pv.w * b) * ATT_SCALE));

    t = *(const float2*)&kp[2 * p];
    ss = fmaf(t.x, t.x, t.y * t.y);
    #pragma unroll
    for (int off = 32; off; off >>= 1) ss += __shfl_xor(ss, off);
    r = rsqrtf(ss * (1.f / DH) + EPSF);
    a = t.x * r * ks2.x; b = t.y * r * ks2.y;
    *(ushort2*)&kb[((size_t)h * L_SEQ + l) * DH + 2 * p] =
        make_ushort2(f2bf(fmaf(pv.x, a, pv.y * b)), f2bf(fmaf(pv.z, a, pv.w * b)));
}

// ---------------- flash attention, bf16 MFMA ------------------------------
// 4 waves/block; each wave owns 16 q rows; KV tile = 64. K/Vt staged via
// global_load_lds with XOR-swizzled (16B-chunk ^ (row&7)) source so the
// strided fragment reads are bank-conflict-free (<=2-way).
__global__ __launch_bounds__(256)
void attn_mfma(const unsigned short* __restrict__ qb,
               const unsigned short* __restrict__ kb,
               const unsigned short* __restrict__ vt,
               unsigned short* __restrict__ a2) {
    __shared__ unsigned short Ks[64 * 128];   // [kv row][d], swizzled
    __shared__ unsigned short Vts[128 * 64];  // [d][kv row], swizzled
    __shared__ unsigned short Ps[4][16][72];  // per-wave P tile, padded
    const int h = blockIdx.y;
    const int q0 = blockIdx.x * 64;
    const int tid = threadIdx.x;
    const int w = tid >> 6, lane = tid & 63;
    const int quad = lane >> 4, lr = lane & 15;
    const unsigned short* Qp = qb + (size_t)h * L_SEQ * DH;
    const unsigned short* Kp = kb + (size_t)h * L_SEQ * DH;
    const unsigned short* Vp = vt + (size_t)h * DH * L_SEQ;

    // Q fragments (A-layout): lane(q*16+l) holds Q[l][c*32+q*8 ..+7]
    bf16x8 qf[4];
    #pragma unroll
    for (int c = 0; c < 4; c++)
        qf[c] = *(const bf16x8*)&Qp[(size_t)(q0 + w * 16 + lr) * DH + c * 32 + quad * 8];

    f32x4 acc[8] = {};
    float m[4], lsum[4];
    #pragma unroll
    for (int r = 0; r < 4; r++) { m[r] = -1e30f; lsum[r] = 0.f; }

    for (int kt = 0; kt < L_SEQ; kt += 64) {
        __syncthreads();                       // LDS reuse fence
        #pragma unroll
        for (int j = 0; j < 4; j++) {          // K: 64 rows x 256B
            const int rb = w * 16 + j * 4;
            const int row = rb + (lane >> 4);
            const int lc = (lane & 15) ^ (row & 7);
            gload_lds16(&Kp[(size_t)(kt + row) * DH + lc * 8], &Ks[rb * 128]);
        }
        #pragma unroll
        for (int j = 0; j < 4; j++) {          // Vt: 128 rows x 128B
            const int rb = w * 32 + j * 8;
            const int row = rb + (lane >> 3);
            const int lc = (lane & 7) ^ (row & 7);
            gload_lds16(&Vp[(size_t)row * L_SEQ + kt + lc * 8], &Vts[rb * 64]);
        }
        __syncthreads();                       // vmcnt drained by barrier

        // S = Q K^T  (rows: wave's 16 q; cols: 64 kv)
        f32x4 s[4] = {};
        #pragma unroll
        for (int c = 0; c < 4; c++) {
            #pragma unroll
            for (int n = 0; n < 4; n++) {
                const int row = n * 16 + lr;
                const bf16x8 kf = *(const bf16x8*)
                    &Ks[row * 128 + (((c * 4 + quad) ^ (row & 7)) * 8)];
                s[n] = __builtin_amdgcn_mfma_f32_16x16x32_bf16(qf[c], kf, s[n], 0, 0, 0);
            }
        }

        // online softmax (rows quad*4+r, spread over 16 lanes of the quad)
        float alpha[4];
        #pragma unroll
        for (int r = 0; r < 4; r++) {
            float t = fmaxf(fmaxf(s[0][r], s[1][r]), fmaxf(s[2][r], s[3][r]));
            t = fmaxf(t, __shfl_xor(t, 1));
            t = fmaxf(t, __shfl_xor(t, 2));
            t = fmaxf(t, __shfl_xor(t, 4));
            t = fmaxf(t, __shfl_xor(t, 8));
            const float mn = fmaxf(m[r], t);
            alpha[r] = __expf(m[r] - mn);
            m[r] = mn;
        }
        float psum[4] = {0.f, 0.f, 0.f, 0.f};
        #pragma unroll
        for (int n = 0; n < 4; n++) {
            #pragma unroll
            for (int r = 0; r < 4; r++) {
                const float p = __expf(s[n][r] - m[r]);
                psum[r] += p;
                Ps[w][quad * 4 + r][n * 16 + lr] = f2bf(p);
            }
        }
        #pragma unroll
        for (int r = 0; r < 4; r++) {
            float t = psum[r];
            t += __shfl_xor(t, 1); t += __shfl_xor(t, 2);
            t += __shfl_xor(t, 4); t += __shfl_xor(t, 8);
            lsum[r] = lsum[r] * alpha[r] + t;
        }
        #pragma unroll
        for (int dt = 0; dt < 8; dt++)
            #pragma unroll
            for (int r = 0; r < 4; r++) acc[dt][r] *= alpha[r];

        // O += P V  (A = P from LDS, B = Vt rows)
        #pragma unroll
        for (int jc = 0; jc < 2; jc++) {
            const bf16x8 pf = *(const bf16x8*)&Ps[w][lr][jc * 32 + quad * 8];
            #pragma unroll
            for (int dt = 0; dt < 8; dt++) {
                const int row = dt * 16 + lr;
                const bf16x8 vf = *(const bf16x8*)
                    &Vts[row * 64 + (((jc * 4 + quad) ^ (row & 7)) * 8)];
                acc[dt] = __builtin_amdgcn_mfma_f32_16x16x32_bf16(pf, vf, acc[dt], 0, 0, 0);
            }
        }
    }

    float inv[4];
    #pragma unroll
    for (int r = 0; r < 4; r++) inv[r] = 1.f / lsum[r];
    unsigned short* orow = a2 + (size_t)(q0 + w * 16) * K2 + h * DH;
    #pragma unroll
    for (int dt = 0; dt < 8; dt++)
        #pragma unroll
        for (int r = 0; r < 4; r++)
            orow[(size_t)(quad * 4 + r) * K2 + dt * 16 + lr] = f2bf(acc[dt][r] * inv[r]);
}

// ---------------------------------------------------------------------------
extern "C" void kernel_launch(void* const* d_in, const int* in_sizes, int n_in,
                              void* d_out, int out_size, void* d_ws, size_t ws_size,
                              hipStream_t stream) {
    (void)in_sizes; (void)n_in; (void)out_size; (void)ws_size;
    const float* x      = (const float*)d_in[0];
    const float* vec    = (const float*)d_in[1];
    const float* pe     = (const float*)d_in[2];
    const float* mod_w  = (const float*)d_in[3];
    const float* mod_b  = (const float*)d_in[4];
    const float* gamma  = (const float*)d_in[5];
    const float* beta   = (const float*)d_in[6];
    const float* w1     = (const float*)d_in[7];
    const float* b1     = (const float*)d_in[8];
    const float* q_s    = (const float*)d_in[9];
    const float* k_s    = (const float*)d_in[10];
    const float* w2     = (const float*)d_in[11];
    const float* b2     = (const float*)d_in[12];
    float* out = (float*)d_out;

    char* ws = (char*)d_ws;
    size_t off = 0;
    float* modbuf = (float*)(ws + off);                  off += 40960;
    unsigned short* x_mod = (unsigned short*)(ws + off); off += (size_t)L_SEQ * HID * 2;
    float* qkv = (float*)(ws + off);                     off += (size_t)2 * NH * L_SEQ * DH * 4;
    unsigned short* qb  = (unsigned short*)(ws + off);   off += (size_t)NH * L_SEQ * DH * 2;
    unsigned short* kb  = (unsigned short*)(ws + off);   off += (size_t)NH * L_SEQ * DH * 2;
    unsigned short* vtb = (unsigned short*)(ws + off);   off += (size_t)NH * L_SEQ * DH * 2;
    unsigned short* a2  = (unsigned short*)(ws + off);   off += (size_t)L_SEQ * K2 * 2;
    unsigned short* w1t = (unsigned short*)(ws + off);   off += (size_t)N1 * HID * 2;
    unsigned short* w2t = (unsigned short*)(ws + off);   off += (size_t)HID * K2 * 2;

    // weight convert+transpose (bf16, [N][K])
    k_convT<<<dim3(N1 / 64, HID / 64), 256, 0, stream>>>(w1, w1t, HID, N1);
    k_convT<<<dim3(HID / 64, K2 / 64), 256, 0, stream>>>(w2, w2t, K2, HID);

    hipMemsetAsync(modbuf, 0, 9216 * sizeof(float), stream);
    k_mod<<<dim3(36, 8), 256, 0, stream>>>(vec, mod_w, mod_b, modbuf);
    k_ln<<<L_SEQ, 256, 0, stream>>>(x, modbuf, gamma, beta, x_mod);

    gemm_bt<0><<<dim3(N1 / 128, L_SEQ / 128), 256, 0, stream>>>(
        x_mod, w1t, b1, HID, qkv, vtb, a2, nullptr, nullptr, nullptr);

    k_rmsrope<<<NH * L_SEQ, 64, 0, stream>>>(qkv, pe, q_s, k_s, qb, kb);
    attn_mfma<<<dim3(L_SEQ / 64, NH), 256, 0, stream>>>(qb, kb, vtb, a2);

    gemm_bt<1><<<dim3(HID / 128, L_SEQ / 128), 256, 0, stream>>>(
        a2, w2t, b2, K2, nullptr, nullptr, nullptr, x, modbuf, out);
}

// Round 2
// 1340.781 us; speedup vs baseline: 2.4047x; 1.1825x over previous
//
#include <hip/hip_runtime.h>
#include <hip/hip_bf16.h>
#include <cstdint>

// Problem dims (B=1)
#define L_SEQ 2048
#define NH    24
#define DH    128
#define HID   3072          // NH*DH
#define MLPD  12288         // 4*HID
#define N1    21504         // 3*HID + MLP
#define K2    15360         // HID + MLP
#define EPSF  1e-6f
#define ATT_SCALE 0.08838834764831845f

typedef __bf16 bf16x8 __attribute__((ext_vector_type(8)));
typedef float  f32x4  __attribute__((ext_vector_type(4)));

__device__ __forceinline__ float gelu_tanh(float x) {
    float x3 = x * x * x;
    return 0.5f * x * (1.f + tanhf(0.7978845608028654f * (x + 0.044715f * x3)));
}

// float -> bf16 bits, round-to-nearest-even (finite inputs)
__device__ __forceinline__ unsigned short f2bf(float f) {
    union { float f; unsigned int u; } x{f};
    unsigned int r = x.u + 0x7fffu + ((x.u >> 16) & 1u);
    return (unsigned short)(r >> 16);
}

// async global->LDS, 16B per lane; LDS dest is wave-uniform base + lane*16
__device__ __forceinline__ void gload_lds16(const void* g, void* l) {
    __builtin_amdgcn_global_load_lds(
        (__attribute__((address_space(1))) void*)g,
        (__attribute__((address_space(3))) void*)l, 16, 0, 0);
}

// ---------------- fp32 [R][C] -> bf16 [C][R] tile transpose ---------------
__global__ __launch_bounds__(256)
void k_convT(const float* __restrict__ in, unsigned short* __restrict__ out,
             int R, int C) {
    __shared__ unsigned short s[64][72];
    const int r0 = blockIdx.y * 64, c0 = blockIdx.x * 64;
    const int tid = threadIdx.x;
    const int row = tid >> 4, c4 = (tid & 15) * 4;
    #pragma unroll
    for (int rr = 0; rr < 4; rr++) {
        int r = row + rr * 16;
        float4 v = *(const float4*)&in[(size_t)(r0 + r) * C + c0 + c4];
        s[r][c4 + 0] = f2bf(v.x); s[r][c4 + 1] = f2bf(v.y);
        s[r][c4 + 2] = f2bf(v.z); s[r][c4 + 3] = f2bf(v.w);
    }
    __syncthreads();
    #pragma unroll
    for (int rr = 0; rr < 4; rr++) {
        int oc = row + rr * 16;          // tile-col index (out row)
        ushort4 t = make_ushort4(s[c4 + 0][oc], s[c4 + 1][oc],
                                 s[c4 + 2][oc], s[c4 + 3][oc]);
        *(ushort4*)&out[(size_t)(c0 + oc) * R + r0 + c4] = t;
    }
}

// ---------------- mod = silu(vec) @ mod_w + mod_b  (split-K + atomics) -----
__global__ __launch_bounds__(256)
void k_mod(const float* __restrict__ vec, const float* __restrict__ mod_w,
           const float* __restrict__ mod_b, float* __restrict__ mod) {
    __shared__ float sv[384];
    const int j  = blockIdx.x * 256 + threadIdx.x;   // 0..9215
    const int k0 = blockIdx.y * 384;
    for (int i = threadIdx.x; i < 384; i += 256) {
        float v = vec[k0 + i];
        sv[i] = v / (1.f + __expf(-v));
    }
    __syncthreads();
    float acc = (blockIdx.y == 0) ? mod_b[j] : 0.f;
    #pragma unroll 8
    for (int i = 0; i < 384; i++)
        acc = fmaf(sv[i], mod_w[(size_t)(k0 + i) * 9216 + j], acc);
    atomicAdd(&mod[j], acc);
}

// ---------------- LayerNorm + modulate -> bf16 ----------------------------
__global__ __launch_bounds__(256)
void k_ln(const float* __restrict__ x, const float* __restrict__ mod,
          const float* __restrict__ gamma, const float* __restrict__ beta,
          unsigned short* __restrict__ x_mod) {
    __shared__ float rs_[4], rs2_[4];
    const int l = blockIdx.x, tid = threadIdx.x;
    const float* xr = x + (size_t)l * HID;
    float s = 0.f, s2 = 0.f;
    for (int i = tid; i < HID; i += 256) {
        float v = xr[i]; s += v; s2 = fmaf(v, v, s2);
    }
    #pragma unroll
    for (int off = 32; off; off >>= 1) { s += __shfl_xor(s, off); s2 += __shfl_xor(s2, off); }
    const int w = tid >> 6;
    if ((tid & 63) == 0) { rs_[w] = s; rs2_[w] = s2; }
    __syncthreads();
    s  = rs_[0] + rs_[1] + rs_[2] + rs_[3];
    s2 = rs2_[0] + rs2_[1] + rs2_[2] + rs2_[3];
    float mu   = s * (1.f / HID);
    float var  = s2 * (1.f / HID) - mu * mu;
    float rstd = rsqrtf(var + EPSF);
    unsigned short* orow = x_mod + (size_t)l * HID;
    for (int i = tid; i < HID; i += 256) {
        float ln = (xr[i] - mu) * rstd * gamma[i] + beta[i];
        orow[i] = f2bf(fmaf(1.f + mod[HID + i], ln, mod[i]));
    }
}

// ======================= 256x256x64 8-phase bf16 GEMM ======================
// 8 waves (512 thr), per-wave C = 128x64 via interleaved mapping:
//   row = mh*128 + i*32 + wm*16 (+quad*4+r),  col = nh*128 + j*64 + wn*16 (+lr)
// Phases per K-tile: quadrants (0,0)(1,0)(1,1)(0,1); each phase stages ONE
// half-tile of K-tile kt+1 (A0,B0,A1,B1), vmcnt(4) + raw s_barrier per phase
// => 2-3 half-tiles always in flight, never a full drain.
// LDS: A[2][256][64] + B[2][256][64] bf16 = 128 KiB dynamic, 16B-chunk
// XOR-swizzle ^(row&7) on stage source and ds_read (conflict-free reads).
// MODE 0: x_mod @ w1t^T -> q,k fp32 scatter, v bf16 [h][d][l], gelu(mlp)->a2
// MODE 1 (split-K over blockIdx.z): a2 @ w2t^T -> fp32 partials
template<int MODE>
__global__ __launch_bounds__(512, 2)
void gemm8(const unsigned short* __restrict__ A,
           const unsigned short* __restrict__ Bt,
           const float* __restrict__ bias, int K, int nkt,
           float* __restrict__ qkv, unsigned short* __restrict__ vt,
           unsigned short* __restrict__ a2, float* __restrict__ part) {
    extern __shared__ unsigned short sm[];
    unsigned short* As = sm;            // [2][256][64]
    unsigned short* Bs = sm + 32768;    // [2][256][64]
    const int tid = threadIdx.x;
    const int w = tid >> 6, lane = tid & 63;
    const int wm = w >> 2, wn = w & 3;
    const int quad = lane >> 4, lr = lane & 15;
    const int bm = blockIdx.y * 256, bn = blockIdx.x * 256;
    const int koff = (MODE == 1) ? blockIdx.z * (K >> 1) : 0;

    f32x4 acc[8][4] = {};
    bf16x8 a_[4][2], b_[2][2];

#define STG(SEL, HM, KT, D) do {                                             \
    const unsigned short* gp_ = (SEL) ? Bt : A;                              \
    const int gb_ = (SEL) ? bn : bm;                                         \
    unsigned short* ls_ = ((SEL) ? Bs : As) + (D) * 16384 + (HM) * 8192      \
                          + ((tid & ~63) << 3);                              \
    _Pragma("unroll")                                                        \
    for (int q_ = 0; q_ < 2; q_++) {                                         \
        int idx_ = q_ * 512 + tid;                                           \
        int r_   = (HM) * 128 + (idx_ >> 3);                                 \
        gload_lds16(&gp_[(size_t)(gb_ + r_) * K + koff + (KT) * 64           \
                         + (((idx_ & 7) ^ (r_ & 7)) << 3)],                  \
                    ls_ + q_ * 4096);                                        \
    }                                                                        \
} while (0)

#define LDA(MH, D) do {                                                      \
    _Pragma("unroll")                                                        \
    for (int i_ = 0; i_ < 4; i_++)                                           \
    _Pragma("unroll")                                                        \
    for (int ks_ = 0; ks_ < 2; ks_++) {                                      \
        int r_ = (MH) * 128 + i_ * 32 + wm * 16 + lr;                        \
        int c_ = ks_ * 4 + quad;                                             \
        a_[i_][ks_] = *(const bf16x8*)&As[(D) * 16384 + r_ * 64              \
                                          + ((c_ ^ (r_ & 7)) << 3)];         \
    }                                                                        \
} while (0)

#define LDB(NH, D) do {                                                      \
    _Pragma("unroll")                                                        \
    for (int j_ = 0; j_ < 2; j_++)                                           \
    _Pragma("unroll")                                                        \
    for (int ks_ = 0; ks_ < 2; ks_++) {                                      \
        int r_ = (NH) * 128 + j_ * 64 + wn * 16 + lr;                        \
        int c_ = ks_ * 4 + quad;                                             \
        b_[j_][ks_] = *(const bf16x8*)&Bs[(D) * 16384 + r_ * 64              \
                                          + ((c_ ^ (r_ & 7)) << 3)];         \
    }                                                                        \
} while (0)

#define MM(MH, NH) do {                                                      \
    __builtin_amdgcn_s_setprio(1);                                           \
    _Pragma("unroll")                                                        \
    for (int i_ = 0; i_ < 4; i_++)                                           \
    _Pragma("unroll")                                                        \
    for (int j_ = 0; j_ < 2; j_++)                                           \
    _Pragma("unroll")                                                        \
    for (int ks_ = 0; ks_ < 2; ks_++)                                        \
        acc[(MH) * 4 + i_][(NH) * 2 + j_] =                                  \
            __builtin_amdgcn_mfma_f32_16x16x32_bf16(                         \
                a_[i_][ks_], b_[j_][ks_],                                    \
                acc[(MH) * 4 + i_][(NH) * 2 + j_], 0, 0, 0);                 \
    __builtin_amdgcn_s_setprio(0);                                           \
} while (0)

#define SYNC1 do { asm volatile("s_waitcnt vmcnt(4)" ::: "memory");          \
    __builtin_amdgcn_s_barrier(); __builtin_amdgcn_sched_barrier(0); } while (0)
#define SYNC2 do { asm volatile("" ::: "memory");                            \
    __builtin_amdgcn_s_barrier(); __builtin_amdgcn_sched_barrier(0); } while (0)

    // prologue: stage tile0 (A0,B0,A1,B1) -> buf0; wait first two halves
    STG(0, 0, 0, 0); STG(1, 0, 0, 0); STG(0, 1, 0, 0); STG(1, 1, 0, 0);
    SYNC1;

    for (int kt = 0; kt < nkt; ++kt) {
        const int d = kt & 1, dn = d ^ 1;
        const int ktn = (kt + 1 < nkt) ? kt + 1 : 0;   // tail: harmless re-stage
        // ph1: quadrant (0,0)
        LDA(0, d); LDB(0, d);
        STG(0, 0, ktn, dn);
        SYNC1; MM(0, 0); SYNC2;
        // ph2: quadrant (1,0)
        LDA(1, d);
        STG(1, 0, ktn, dn);
        SYNC1; MM(1, 0); SYNC2;
        // ph3: quadrant (1,1)
        LDB(1, d);
        STG(0, 1, ktn, dn);
        SYNC1; MM(1, 1); SYNC2;
        // ph4: quadrant (0,1)
        LDA(0, d);
        STG(1, 1, ktn, dn);
        SYNC1; MM(0, 1); SYNC2;
    }

#undef STG
#undef LDA
#undef LDB
#undef MM
#undef SYNC1
#undef SYNC2

    float* pz = (MODE == 1) ? part + (size_t)blockIdx.z * L_SEQ * HID : nullptr;

    #pragma unroll
    for (int mh = 0; mh < 2; mh++)
    #pragma unroll
    for (int i = 0; i < 4; i++)
    #pragma unroll
    for (int nh = 0; nh < 2; nh++)
    #pragma unroll
    for (int j = 0; j < 2; j++) {
        const int col  = bn + nh * 128 + j * 64 + wn * 16 + lr;
        const int row0 = bm + mh * 128 + i * 32 + wm * 16 + quad * 4;
        const f32x4 v4 = acc[mh * 4 + i][nh * 2 + j];
        if (MODE == 0) {
            const float bs = bias[col];
            #pragma unroll
            for (int r = 0; r < 4; r++) {
                const int row = row0 + r;
                float v = v4[r] + bs;
                if (col < 2 * HID) {
                    int s3 = col / HID, rem = col - s3 * HID;
                    int hh = rem >> 7, dd = rem & 127;
                    qkv[(((size_t)s3 * NH + hh) * L_SEQ + row) * DH + dd] = v;
                } else if (col < 3 * HID) {
                    int rem = col - 2 * HID;
                    int hh = rem >> 7, dd = rem & 127;
                    vt[((size_t)hh * DH + dd) * L_SEQ + row] = f2bf(v);
                } else {
                    a2[(size_t)row * K2 + col - 6144] = f2bf(gelu_tanh(v));
                }
            }
        } else {
            #pragma unroll
            for (int r = 0; r < 4; r++)
                pz[(size_t)(row0 + r) * HID + col] = v4[r];
        }
    }
}

// ---------------- final: out = x + gate*(p0 + p1 + b2) --------------------
__global__ __launch_bounds__(256)
void k_fin(const float* __restrict__ p, const float* __restrict__ x,
           const float* __restrict__ mod, const float* __restrict__ b2,
           float* __restrict__ out) {
    const int col = blockIdx.x * 1024 + threadIdx.x * 4;
    const size_t i = (size_t)blockIdx.y * HID + col;
    float4 a  = *(const float4*)&p[i];
    float4 b  = *(const float4*)&p[(size_t)L_SEQ * HID + i];
    float4 xr = *(const float4*)&x[i];
    float4 g  = *(const float4*)&mod[2 * HID + col];
    float4 bb = *(const float4*)&b2[col];
    float4 o;
    o.x = fmaf(g.x, a.x + b.x + bb.x, xr.x);
    o.y = fmaf(g.y, a.y + b.y + bb.y, xr.y);
    o.z = fmaf(g.z, a.z + b.z + bb.z, xr.z);
    o.w = fmaf(g.w, a.w + b.w + bb.w, xr.w);
    *(float4*)&out[i] = o;
}

// ---------------- RMSNorm(q,k) + RoPE  (fp32 in, bf16 out) ----------------
// q additionally pre-scaled by 1/sqrt(D) so attn QK^T needs no scale.
__global__ __launch_bounds__(64)
void k_rmsrope(const float* __restrict__ qkv, const float* __restrict__ pe,
               const float* __restrict__ qsc, const float* __restrict__ ksc,
               unsigned short* __restrict__ qb, unsigned short* __restrict__ kb) {
    const int idx = blockIdx.x;            // h*L + l
    const int h = idx >> 11, l = idx & 2047;
    const int p = threadIdx.x;             // pair index 0..63
    const float* qp = qkv + ((size_t)h * L_SEQ + l) * DH;
    const float* kp = qkv + ((size_t)(NH + h) * L_SEQ + l) * DH;
    const float4 pv = *(const float4*)&pe[((size_t)l * 64 + p) * 4];
    const float2 qs2 = *(const float2*)&qsc[2 * p];
    const float2 ks2 = *(const float2*)&ksc[2 * p];

    float2 t = *(const float2*)&qp[2 * p];
    float ss = fmaf(t.x, t.x, t.y * t.y);
    #pragma unroll
    for (int off = 32; off; off >>= 1) ss += __shfl_xor(ss, off);
    float r = rsqrtf(ss * (1.f / DH) + EPSF);
    float a = t.x * r * qs2.x, b = t.y * r * qs2.y;
    *(ushort2*)&qb[((size_t)h * L_SEQ + l) * DH + 2 * p] =
        make_ushort2(f2bf(fmaf(pv.x, a, pv.y * b) * ATT_SCALE),
                     f2bf(fmaf(pv.z, a, pv.w * b) * ATT_SCALE));

    t = *(const float2*)&kp[2 * p];
    ss = fmaf(t.x, t.x, t.y * t.y);
    #pragma unroll
    for (int off = 32; off; off >>= 1) ss += __shfl_xor(ss, off);
    r = rsqrtf(ss * (1.f / DH) + EPSF);
    a = t.x * r * ks2.x; b = t.y * r * ks2.y;
    *(ushort2*)&kb[((size_t)h * L_SEQ + l) * DH + 2 * p] =
        make_ushort2(f2bf(fmaf(pv.x, a, pv.y * b)), f2bf(fmaf(pv.z, a, pv.w * b)));
}

// ---------------- flash attention, bf16 MFMA, pipelined -------------------
// 4 waves/block; wave owns 16 q rows; KV tile = 64. K double-buffered;
// per tile: raw barrier -> stage V(kt)+K(kt+1) -> QK^T -> softmax ->
// vmcnt(4)+barrier (V landed, K in flight) -> PV. No full drains mid-loop.
__global__ __launch_bounds__(256)
void attn_mfma(const unsigned short* __restrict__ qb,
               const unsigned short* __restrict__ kb,
               const unsigned short* __restrict__ vt,
               unsigned short* __restrict__ a2) {
    __shared__ unsigned short Ks[2][64 * 128]; // [kv row][d], swizzled (32KB)
    __shared__ unsigned short Vts[128 * 64];   // [d][kv row], swizzled (16KB)
    __shared__ unsigned short Ps[4][16][72];   // per-wave P tile, padded
    const int h = blockIdx.y;
    const int q0 = blockIdx.x * 64;
    const int tid = threadIdx.x;
    const int w = tid >> 6, lane = tid & 63;
    const int quad = lane >> 4, lr = lane & 15;
    const unsigned short* Qp = qb + (size_t)h * L_SEQ * DH;
    const unsigned short* Kp = kb + (size_t)h * L_SEQ * DH;
    const unsigned short* Vp = vt + (size_t)h * DH * L_SEQ;

    // Q fragments (A-layout): lane(q*16+l) holds Q[l][c*32+q*8 ..+7]
    bf16x8 qf[4];
    #pragma unroll
    for (int c = 0; c < 4; c++)
        qf[c] = *(const bf16x8*)&Qp[(size_t)(q0 + w * 16 + lr) * DH + c * 32 + quad * 8];

    // prologue: stage K(0) -> Ks[0]
    #pragma unroll
    for (int j = 0; j < 4; j++) {
        const int rb = w * 16 + j * 4;
        const int row = rb + (lane >> 4);
        const int lc = (lane & 15) ^ (row & 7);
        gload_lds16(&Kp[(size_t)row * DH + lc * 8], &Ks[0][rb * 128]);
    }

    f32x4 acc[8] = {};
    float m[4], lsum[4];
    #pragma unroll
    for (int r = 0; r < 4; r++) { m[r] = -1e30f; lsum[r] = 0.f; }

    for (int kt = 0; kt < L_SEQ; kt += 64) {
        const int d = (kt >> 6) & 1;
        const int ktn = (kt + 64 < L_SEQ) ? kt + 64 : 0;  // tail: harmless
        asm volatile("s_waitcnt vmcnt(0)" ::: "memory");  // K(kt) landed
        __builtin_amdgcn_s_barrier();
        __builtin_amdgcn_sched_barrier(0);
        // stage V(kt) first (covered by vmcnt(4) below), then K(kt+1)
        #pragma unroll
        for (int j = 0; j < 4; j++) {
            const int rb = w * 32 + j * 8;
            const int row = rb + (lane >> 3);
            const int lc = (lane & 7) ^ (row & 7);
            gload_lds16(&Vp[(size_t)row * L_SEQ + kt + lc * 8], &Vts[rb * 64]);
        }
        #pragma unroll
        for (int j = 0; j < 4; j++) {
            const int rb = w * 16 + j * 4;
            const int row = rb + (lane >> 4);
            const int lc = (lane & 15) ^ (row & 7);
            gload_lds16(&Kp[(size_t)(ktn + row) * DH + lc * 8], &Ks[d ^ 1][rb * 128]);
        }

        // S = Q K^T  (rows: wave's 16 q; cols: 64 kv)
        f32x4 s[4] = {};
        __builtin_amdgcn_s_setprio(1);
        #pragma unroll
        for (int c = 0; c < 4; c++) {
            #pragma unroll
            for (int n = 0; n < 4; n++) {
                const int row = n * 16 + lr;
                const bf16x8 kf = *(const bf16x8*)
                    &Ks[d][row * 128 + (((c * 4 + quad) ^ (row & 7)) * 8)];
                s[n] = __builtin_amdgcn_mfma_f32_16x16x32_bf16(qf[c], kf, s[n], 0, 0, 0);
            }
        }
        __builtin_amdgcn_s_setprio(0);

        // online softmax (rows quad*4+r, spread over 16 lanes of the quad)
        float alpha[4];
        #pragma unroll
        for (int r = 0; r < 4; r++) {
            float t = fmaxf(fmaxf(s[0][r], s[1][r]), fmaxf(s[2][r], s[3][r]));
            t = fmaxf(t, __shfl_xor(t, 1));
            t = fmaxf(t, __shfl_xor(t, 2));
            t = fmaxf(t, __shfl_xor(t, 4));
            t = fmaxf(t, __shfl_xor(t, 8));
            const float mn = fmaxf(m[r], t);
            alpha[r] = __expf(m[r] - mn);
            m[r] = mn;
        }
        float psum[4] = {0.f, 0.f, 0.f, 0.f};
        #pragma unroll
        for (int n = 0; n < 4; n++) {
            #pragma unroll
            for (int r = 0; r < 4; r++) {
                const float p = __expf(s[n][r] - m[r]);
                psum[r] += p;
                Ps[w][quad * 4 + r][n * 16 + lr] = f2bf(p);
            }
        }
        #pragma unroll
        for (int r = 0; r < 4; r++) {
            float t = psum[r];
            t += __shfl_xor(t, 1); t += __shfl_xor(t, 2);
            t += __shfl_xor(t, 4); t += __shfl_xor(t, 8);
            lsum[r] = lsum[r] * alpha[r] + t;
        }
        #pragma unroll
        for (int dt = 0; dt < 8; dt++)
            #pragma unroll
            for (int r = 0; r < 4; r++) acc[dt][r] *= alpha[r];

        // V(kt) landed (oldest 4 loads); K(kt+1) may stay in flight
        asm volatile("s_waitcnt vmcnt(4)" ::: "memory");
        __builtin_amdgcn_s_barrier();
        __builtin_amdgcn_sched_barrier(0);

        // O += P V  (A = P from LDS, B = Vt rows)
        __builtin_amdgcn_s_setprio(1);
        #pragma unroll
        for (int jc = 0; jc < 2; jc++) {
            const bf16x8 pf = *(const bf16x8*)&Ps[w][lr][jc * 32 + quad * 8];
            #pragma unroll
            for (int dt = 0; dt < 8; dt++) {
                const int row = dt * 16 + lr;
                const bf16x8 vf = *(const bf16x8*)
                    &Vts[row * 64 + (((jc * 4 + quad) ^ (row & 7)) * 8)];
                acc[dt] = __builtin_amdgcn_mfma_f32_16x16x32_bf16(pf, vf, acc[dt], 0, 0, 0);
            }
        }
        __builtin_amdgcn_s_setprio(0);
    }

    float inv[4];
    #pragma unroll
    for (int r = 0; r < 4; r++) inv[r] = 1.f / lsum[r];
    unsigned short* orow = a2 + (size_t)(q0 + w * 16) * K2 + h * DH;
    #pragma unroll
    for (int dt = 0; dt < 8; dt++)
        #pragma unroll
        for (int r = 0; r < 4; r++)
            orow[(size_t)(quad * 4 + r) * K2 + dt * 16 + lr] = f2bf(acc[dt][r] * inv[r]);
}

// ---------------------------------------------------------------------------
extern "C" void kernel_launch(void* const* d_in, const int* in_sizes, int n_in,
                              void* d_out, int out_size, void* d_ws, size_t ws_size,
                              hipStream_t stream) {
    (void)in_sizes; (void)n_in; (void)out_size; (void)ws_size;
    const float* x      = (const float*)d_in[0];
    const float* vec    = (const float*)d_in[1];
    const float* pe     = (const float*)d_in[2];
    const float* mod_w  = (const float*)d_in[3];
    const float* mod_b  = (const float*)d_in[4];
    const float* gamma  = (const float*)d_in[5];
    const float* beta   = (const float*)d_in[6];
    const float* w1     = (const float*)d_in[7];
    const float* b1     = (const float*)d_in[8];
    const float* q_s    = (const float*)d_in[9];
    const float* k_s    = (const float*)d_in[10];
    const float* w2     = (const float*)d_in[11];
    const float* b2     = (const float*)d_in[12];
    float* out = (float*)d_out;

    char* ws = (char*)d_ws;
    size_t off = 0;
    float* modbuf = (float*)(ws + off);                  off += 40960;
    unsigned short* x_mod = (unsigned short*)(ws + off); off += (size_t)L_SEQ * HID * 2;
    float* qkv = (float*)(ws + off);                     off += (size_t)2 * NH * L_SEQ * DH * 4;
    unsigned short* qb  = (unsigned short*)(ws + off);   off += (size_t)NH * L_SEQ * DH * 2;
    unsigned short* kb  = (unsigned short*)(ws + off);   off += (size_t)NH * L_SEQ * DH * 2;
    unsigned short* vtb = (unsigned short*)(ws + off);   off += (size_t)NH * L_SEQ * DH * 2;
    unsigned short* a2  = (unsigned short*)(ws + off);   off += (size_t)L_SEQ * K2 * 2;
    unsigned short* w1t = (unsigned short*)(ws + off);   off += (size_t)N1 * HID * 2;
    unsigned short* w2t = (unsigned short*)(ws + off);   off += (size_t)HID * K2 * 2;
    // split-K partials alias qkv (dead after k_rmsrope): 2*2048*3072*4 bytes
    float* part = qkv;

    static bool s_init = false;
    if (!s_init) {
        s_init = true;
        hipFuncSetAttribute(reinterpret_cast<const void*>(&gemm8<0>),
                            hipFuncAttributeMaxDynamicSharedMemorySize, 131072);
        hipFuncSetAttribute(reinterpret_cast<const void*>(&gemm8<1>),
                            hipFuncAttributeMaxDynamicSharedMemorySize, 131072);
    }

    // weight convert+transpose (bf16, [N][K])
    k_convT<<<dim3(N1 / 64, HID / 64), 256, 0, stream>>>(w1, w1t, HID, N1);
    k_convT<<<dim3(HID / 64, K2 / 64), 256, 0, stream>>>(w2, w2t, K2, HID);

    hipMemsetAsync(modbuf, 0, 9216 * sizeof(float), stream);
    k_mod<<<dim3(36, 8), 256, 0, stream>>>(vec, mod_w, mod_b, modbuf);
    k_ln<<<L_SEQ, 256, 0, stream>>>(x, modbuf, gamma, beta, x_mod);

    gemm8<0><<<dim3(N1 / 256, L_SEQ / 256, 1), 512, 131072, stream>>>(
        x_mod, w1t, b1, HID, HID / 64, qkv, vtb, a2, nullptr);

    k_rmsrope<<<NH * L_SEQ, 64, 0, stream>>>(qkv, pe, q_s, k_s, qb, kb);
    attn_mfma<<<dim3(L_SEQ / 64, NH), 256, 0, stream>>>(qb, kb, vtb, a2);

    gemm8<1><<<dim3(HID / 256, L_SEQ / 256, 2), 512, 131072, stream>>>(
        a2, w2t, nullptr, K2, K2 / 2 / 64, nullptr, nullptr, nullptr, part);

    k_fin<<<dim3(HID / 1024, L_SEQ), 256, 0, stream>>>(part, x, modbuf, b2, out);
}

// Round 3
// 1289.263 us; speedup vs baseline: 2.5007x; 1.0400x over previous
//
#include <hip/hip_runtime.h>
#include <hip/hip_bf16.h>
#include <cstdint>

// Problem dims (B=1)
#define L_SEQ 2048
#define NH    24
#define DH    128
#define HID   3072          // NH*DH
#define MLPD  12288         // 4*HID
#define N1    21504         // 3*HID + MLP
#define K2    15360         // HID + MLP
#define EPSF  1e-6f
#define ATT_SCALE 0.08838834764831845f

typedef __bf16 bf16x8 __attribute__((ext_vector_type(8)));
typedef float  f32x4  __attribute__((ext_vector_type(4)));

__device__ __forceinline__ float gelu_tanh(float x) {
    float x3 = x * x * x;
    return 0.5f * x * (1.f + tanhf(0.7978845608028654f * (x + 0.044715f * x3)));
}

// float -> bf16 bits, round-to-nearest-even (finite inputs)
__device__ __forceinline__ unsigned short f2bf(float f) {
    union { float f; unsigned int u; } x{f};
    unsigned int r = x.u + 0x7fffu + ((x.u >> 16) & 1u);
    return (unsigned short)(r >> 16);
}

// async global->LDS, 16B per lane; LDS dest is wave-uniform base + lane*16
__device__ __forceinline__ void gload_lds16(const void* g, void* l) {
    __builtin_amdgcn_global_load_lds(
        (__attribute__((address_space(1))) void*)g,
        (__attribute__((address_space(3))) void*)l, 16, 0, 0);
}

// ---------------- fp32 [R][C] -> bf16 [C][R] tile transpose ---------------
__global__ __launch_bounds__(256)
void k_convT(const float* __restrict__ in, unsigned short* __restrict__ out,
             int R, int C) {
    __shared__ unsigned short s[64][72];
    const int r0 = blockIdx.y * 64, c0 = blockIdx.x * 64;
    const int tid = threadIdx.x;
    const int row = tid >> 4, c4 = (tid & 15) * 4;
    #pragma unroll
    for (int rr = 0; rr < 4; rr++) {
        int r = row + rr * 16;
        float4 v = *(const float4*)&in[(size_t)(r0 + r) * C + c0 + c4];
        s[r][c4 + 0] = f2bf(v.x); s[r][c4 + 1] = f2bf(v.y);
        s[r][c4 + 2] = f2bf(v.z); s[r][c4 + 3] = f2bf(v.w);
    }
    __syncthreads();
    #pragma unroll
    for (int rr = 0; rr < 4; rr++) {
        int oc = row + rr * 16;          // tile-col index (out row)
        ushort4 t = make_ushort4(s[c4 + 0][oc], s[c4 + 1][oc],
                                 s[c4 + 2][oc], s[c4 + 3][oc]);
        *(ushort4*)&out[(size_t)(c0 + oc) * R + r0 + c4] = t;
    }
}

// ---------------- mod = silu(vec) @ mod_w + mod_b  (split-K + atomics) -----
__global__ __launch_bounds__(256)
void k_mod(const float* __restrict__ vec, const float* __restrict__ mod_w,
           const float* __restrict__ mod_b, float* __restrict__ mod) {
    __shared__ float sv[384];
    const int j  = blockIdx.x * 256 + threadIdx.x;   // 0..9215
    const int k0 = blockIdx.y * 384;
    for (int i = threadIdx.x; i < 384; i += 256) {
        float v = vec[k0 + i];
        sv[i] = v / (1.f + __expf(-v));
    }
    __syncthreads();
    float acc = (blockIdx.y == 0) ? mod_b[j] : 0.f;
    #pragma unroll 8
    for (int i = 0; i < 384; i++)
        acc = fmaf(sv[i], mod_w[(size_t)(k0 + i) * 9216 + j], acc);
    atomicAdd(&mod[j], acc);
}

// ---------------- LayerNorm + modulate -> bf16 ----------------------------
__global__ __launch_bounds__(256)
void k_ln(const float* __restrict__ x, const float* __restrict__ mod,
          const float* __restrict__ gamma, const float* __restrict__ beta,
          unsigned short* __restrict__ x_mod) {
    __shared__ float rs_[4], rs2_[4];
    const int l = blockIdx.x, tid = threadIdx.x;
    const float* xr = x + (size_t)l * HID;
    float s = 0.f, s2 = 0.f;
    for (int i = tid; i < HID; i += 256) {
        float v = xr[i]; s += v; s2 = fmaf(v, v, s2);
    }
    #pragma unroll
    for (int off = 32; off; off >>= 1) { s += __shfl_xor(s, off); s2 += __shfl_xor(s2, off); }
    const int w = tid >> 6;
    if ((tid & 63) == 0) { rs_[w] = s; rs2_[w] = s2; }
    __syncthreads();
    s  = rs_[0] + rs_[1] + rs_[2] + rs_[3];
    s2 = rs2_[0] + rs2_[1] + rs2_[2] + rs2_[3];
    float mu   = s * (1.f / HID);
    float var  = s2 * (1.f / HID) - mu * mu;
    float rstd = rsqrtf(var + EPSF);
    unsigned short* orow = x_mod + (size_t)l * HID;
    for (int i = tid; i < HID; i += 256) {
        float ln = (xr[i] - mu) * rstd * gamma[i] + beta[i];
        orow[i] = f2bf(fmaf(1.f + mod[HID + i], ln, mod[i]));
    }
}

// ======================= 256x256x64 4-phase bf16 GEMM ======================
// 8 waves (512 thr), per-wave C = 128x64:
//   row = mh*128 + i*32 + wm*16 (+quad*4+r),  col = nh*128 + j*64 + wn*16 (+lr)
// B (both N-halves) held in registers; phases per K-tile (quadrants):
//   ph1 (0,0): stage A0'   reads LDA(0)+LDB(0)   ph2 (0,1): stage B0' reads LDB(1)
//   ph3 (1,1): stage B1'   reads LDA(1)          ph4 (1,0): stage A1' reads none
// ONE barrier per phase (vmcnt(4)+s_barrier). Every phase's ds_reads are
// consumed by its own MFMA before the next barrier, so the next phase's
// stage into the other buffer cannot race. Each staged half is vmcnt-drained
// >=1 barrier before its first ds_read (verified trace, 2 loads/phase).
// LDS: A[2][256][64] + B[2][256][64] bf16 = 128 KiB dynamic, 16B-chunk
// XOR-swizzle ^(row&7) on stage source and ds_read (conflict-free reads).
// MODE 0: x_mod @ w1t^T -> q,k fp32 scatter, v bf16 [h][d][l], gelu(mlp)->a2
// MODE 1 (split-K over z): a2 @ w2t^T -> fp32 partials
template<int MODE>
__global__ __launch_bounds__(512, 2)
void gemm8(const unsigned short* __restrict__ A,
           const unsigned short* __restrict__ Bt,
           const float* __restrict__ bias, int K, int nkt,
           float* __restrict__ qkv, unsigned short* __restrict__ vt,
           unsigned short* __restrict__ a2, float* __restrict__ part) {
    extern __shared__ unsigned short sm[];
    unsigned short* As = sm;            // [2][256][64]
    unsigned short* Bs = sm + 32768;    // [2][256][64]
    const int tid = threadIdx.x;
    const int w = tid >> 6, lane = tid & 63;
    const int wm = w >> 2, wn = w & 3;
    const int quad = lane >> 4, lr = lane & 15;

    // bijective XCD swizzle over the flattened grid (grid sizes % 8 == 0)
    const int nbx = gridDim.x, nby = gridDim.y;
    int f = (blockIdx.z * nby + blockIdx.y) * nbx + blockIdx.x;
    const int cpx = (nbx * nby * gridDim.z) >> 3;
    int sid = (f & 7) * cpx + (f >> 3);
    const int bxi = sid % nbx; int tq = sid / nbx;
    const int byi = tq % nby;  const int bzi = tq / nby;

    const int bm = byi * 256, bn = bxi * 256;
    const int koff = (MODE == 1) ? bzi * (K >> 1) : 0;

    f32x4 acc[8][4] = {};
    bf16x8 a_[4][2], b_[2][2][2];

#define STG(SEL, HM, KT, D) do {                                             \
    const unsigned short* gp_ = (SEL) ? Bt : A;                              \
    const int gb_ = (SEL) ? bn : bm;                                         \
    unsigned short* ls_ = ((SEL) ? Bs : As) + (D) * 16384 + (HM) * 8192      \
                          + ((tid & ~63) << 3);                              \
    _Pragma("unroll")                                                        \
    for (int q_ = 0; q_ < 2; q_++) {                                         \
        int idx_ = q_ * 512 + tid;                                           \
        int r_   = (HM) * 128 + (idx_ >> 3);                                 \
        gload_lds16(&gp_[(size_t)(gb_ + r_) * K + koff + (KT) * 64           \
                         + (((idx_ & 7) ^ (r_ & 7)) << 3)],                  \
                    ls_ + q_ * 4096);                                        \
    }                                                                        \
} while (0)

#define LDA(MH, D) do {                                                      \
    _Pragma("unroll")                                                        \
    for (int i_ = 0; i_ < 4; i_++)                                           \
    _Pragma("unroll")                                                        \
    for (int ks_ = 0; ks_ < 2; ks_++) {                                      \
        int r_ = (MH) * 128 + i_ * 32 + wm * 16 + lr;                        \
        int c_ = ks_ * 4 + quad;                                             \
        a_[i_][ks_] = *(const bf16x8*)&As[(D) * 16384 + r_ * 64              \
                                          + ((c_ ^ (r_ & 7)) << 3)];         \
    }                                                                        \
} while (0)

#define LDB(NHH, D) do {                                                     \
    _Pragma("unroll")                                                        \
    for (int j_ = 0; j_ < 2; j_++)                                           \
    _Pragma("unroll")                                                        \
    for (int ks_ = 0; ks_ < 2; ks_++) {                                      \
        int r_ = (NHH) * 128 + j_ * 64 + wn * 16 + lr;                       \
        int c_ = ks_ * 4 + quad;                                             \
        b_[NHH][j_][ks_] = *(const bf16x8*)&Bs[(D) * 16384 + r_ * 64         \
                                               + ((c_ ^ (r_ & 7)) << 3)];    \
    }                                                                        \
} while (0)

#define MM(MH, NHH) do {                                                     \
    __builtin_amdgcn_s_setprio(1);                                           \
    _Pragma("unroll")                                                        \
    for (int i_ = 0; i_ < 4; i_++)                                           \
    _Pragma("unroll")                                                        \
    for (int j_ = 0; j_ < 2; j_++)                                           \
    _Pragma("unroll")                                                        \
    for (int ks_ = 0; ks_ < 2; ks_++)                                        \
        acc[(MH) * 4 + i_][(NHH) * 2 + j_] =                                 \
            __builtin_amdgcn_mfma_f32_16x16x32_bf16(                         \
                a_[i_][ks_], b_[NHH][j_][ks_],                               \
                acc[(MH) * 4 + i_][(NHH) * 2 + j_], 0, 0, 0);                \
    __builtin_amdgcn_s_setprio(0);                                           \
} while (0)

#define SYNC do { asm volatile("s_waitcnt vmcnt(4)" ::: "memory");           \
    __builtin_amdgcn_s_barrier(); __builtin_amdgcn_sched_barrier(0); } while (0)

    // prologue: stage tile0 (A0,B0,B1,A1) -> buf0; wait first two halves
    STG(0, 0, 0, 0); STG(1, 0, 0, 0); STG(1, 1, 0, 0); STG(0, 1, 0, 0);
    SYNC;

    for (int kt = 0; kt < nkt; ++kt) {
        const int d = kt & 1, dn = d ^ 1;
        const int ktn = (kt + 1 < nkt) ? kt + 1 : 0;   // tail: harmless re-stage
        // ph1: quadrant (0,0)
        STG(0, 0, ktn, dn);
        LDA(0, d); LDB(0, d);
        SYNC; MM(0, 0);
        // ph2: quadrant (0,1)
        STG(1, 0, ktn, dn);
        LDB(1, d);
        SYNC; MM(0, 1);
        // ph3: quadrant (1,1)
        STG(1, 1, ktn, dn);
        LDA(1, d);
        SYNC; MM(1, 1);
        // ph4: quadrant (1,0)
        STG(0, 1, ktn, dn);
        SYNC; MM(1, 0);
    }
    asm volatile("s_waitcnt vmcnt(0)" ::: "memory");   // LDS-dealloc safety

#undef STG
#undef LDA
#undef LDB
#undef MM
#undef SYNC

    float* pz = (MODE == 1) ? part + (size_t)bzi * L_SEQ * HID : nullptr;

    #pragma unroll
    for (int mh = 0; mh < 2; mh++)
    #pragma unroll
    for (int i = 0; i < 4; i++)
    #pragma unroll
    for (int nh = 0; nh < 2; nh++)
    #pragma unroll
    for (int j = 0; j < 2; j++) {
        const int col  = bn + nh * 128 + j * 64 + wn * 16 + lr;
        const int row0 = bm + mh * 128 + i * 32 + wm * 16 + quad * 4;
        const f32x4 v4 = acc[mh * 4 + i][nh * 2 + j];
        if (MODE == 0) {
            const float bs = bias[col];
            #pragma unroll
            for (int r = 0; r < 4; r++) {
                const int row = row0 + r;
                float v = v4[r] + bs;
                if (col < 2 * HID) {
                    int s3 = col / HID, rem = col - s3 * HID;
                    int hh = rem >> 7, dd = rem & 127;
                    qkv[(((size_t)s3 * NH + hh) * L_SEQ + row) * DH + dd] = v;
                } else if (col < 3 * HID) {
                    int rem = col - 2 * HID;
                    int hh = rem >> 7, dd = rem & 127;
                    vt[((size_t)hh * DH + dd) * L_SEQ + row] = f2bf(v);
                } else {
                    a2[(size_t)row * K2 + col - 6144] = f2bf(gelu_tanh(v));
                }
            }
        } else {
            #pragma unroll
            for (int r = 0; r < 4; r++)
                pz[(size_t)(row0 + r) * HID + col] = v4[r];
        }
    }
}

// ---------------- final: out = x + gate*(p0 + p1 + b2) --------------------
__global__ __launch_bounds__(256)
void k_fin(const float* __restrict__ p, const float* __restrict__ x,
           const float* __restrict__ mod, const float* __restrict__ b2,
           float* __restrict__ out) {
    const int col = blockIdx.x * 1024 + threadIdx.x * 4;
    const size_t i = (size_t)blockIdx.y * HID + col;
    float4 a  = *(const float4*)&p[i];
    float4 b  = *(const float4*)&p[(size_t)L_SEQ * HID + i];
    float4 xr = *(const float4*)&x[i];
    float4 g  = *(const float4*)&mod[2 * HID + col];
    float4 bb = *(const float4*)&b2[col];
    float4 o;
    o.x = fmaf(g.x, a.x + b.x + bb.x, xr.x);
    o.y = fmaf(g.y, a.y + b.y + bb.y, xr.y);
    o.z = fmaf(g.z, a.z + b.z + bb.z, xr.z);
    o.w = fmaf(g.w, a.w + b.w + bb.w, xr.w);
    *(float4*)&out[i] = o;
}

// ---------------- RMSNorm(q,k) + RoPE  (fp32 in, bf16 out) ----------------
// q additionally pre-scaled by 1/sqrt(D) so attn QK^T needs no scale.
__global__ __launch_bounds__(64)
void k_rmsrope(const float* __restrict__ qkv, const float* __restrict__ pe,
               const float* __restrict__ qsc, const float* __restrict__ ksc,
               unsigned short* __restrict__ qb, unsigned short* __restrict__ kb) {
    const int idx = blockIdx.x;            // h*L + l
    const int h = idx >> 11, l = idx & 2047;
    const int p = threadIdx.x;             // pair index 0..63
    const float* qp = qkv + ((size_t)h * L_SEQ + l) * DH;
    const float* kp = qkv + ((size_t)(NH + h) * L_SEQ + l) * DH;
    const float4 pv = *(const float4*)&pe[((size_t)l * 64 + p) * 4];
    const float2 qs2 = *(const float2*)&qsc[2 * p];
    const float2 ks2 = *(const float2*)&ksc[2 * p];

    float2 t = *(const float2*)&qp[2 * p];
    float ss = fmaf(t.x, t.x, t.y * t.y);
    #pragma unroll
    for (int off = 32; off; off >>= 1) ss += __shfl_xor(ss, off);
    float r = rsqrtf(ss * (1.f / DH) + EPSF);
    float a = t.x * r * qs2.x, b = t.y * r * qs2.y;
    *(ushort2*)&qb[((size_t)h * L_SEQ + l) * DH + 2 * p] =
        make_ushort2(f2bf(fmaf(pv.x, a, pv.y * b) * ATT_SCALE),
                     f2bf(fmaf(pv.z, a, pv.w * b) * ATT_SCALE));

    t = *(const float2*)&kp[2 * p];
    ss = fmaf(t.x, t.x, t.y * t.y);
    #pragma unroll
    for (int off = 32; off; off >>= 1) ss += __shfl_xor(ss, off);
    r = rsqrtf(ss * (1.f / DH) + EPSF);
    a = t.x * r * ks2.x; b = t.y * r * ks2.y;
    *(ushort2*)&kb[((size_t)h * L_SEQ + l) * DH + 2 * p] =
        make_ushort2(f2bf(fmaf(pv.x, a, pv.y * b)), f2bf(fmaf(pv.z, a, pv.w * b)));
}

// ---------------- flash attention, bf16 MFMA, pipelined -------------------
// 4 waves/block; wave owns 16 q rows; KV tile = 64. K double-buffered;
// per tile: raw barrier -> stage V(kt)+K(kt+1) -> QK^T -> softmax ->
// vmcnt(4)+barrier (V landed, K in flight) -> PV. No full drains mid-loop.
__global__ __launch_bounds__(256)
void attn_mfma(const unsigned short* __restrict__ qb,
               const unsigned short* __restrict__ kb,
               const unsigned short* __restrict__ vt,
               unsigned short* __restrict__ a2) {
    __shared__ unsigned short Ks[2][64 * 128]; // [kv row][d], swizzled (32KB)
    __shared__ unsigned short Vts[128 * 64];   // [d][kv row], swizzled (16KB)
    __shared__ unsigned short Ps[4][16][72];   // per-wave P tile, padded
    const int h = blockIdx.y;
    const int q0 = blockIdx.x * 64;
    const int tid = threadIdx.x;
    const int w = tid >> 6, lane = tid & 63;
    const int quad = lane >> 4, lr = lane & 15;
    const unsigned short* Qp = qb + (size_t)h * L_SEQ * DH;
    const unsigned short* Kp = kb + (size_t)h * L_SEQ * DH;
    const unsigned short* Vp = vt + (size_t)h * DH * L_SEQ;

    // Q fragments (A-layout): lane(q*16+l) holds Q[l][c*32+q*8 ..+7]
    bf16x8 qf[4];
    #pragma unroll
    for (int c = 0; c < 4; c++)
        qf[c] = *(const bf16x8*)&Qp[(size_t)(q0 + w * 16 + lr) * DH + c * 32 + quad * 8];

    // prologue: stage K(0) -> Ks[0]
    #pragma unroll
    for (int j = 0; j < 4; j++) {
        const int rb = w * 16 + j * 4;
        const int row = rb + (lane >> 4);
        const int lc = (lane & 15) ^ (row & 7);
        gload_lds16(&Kp[(size_t)row * DH + lc * 8], &Ks[0][rb * 128]);
    }

    f32x4 acc[8] = {};
    float m[4], lsum[4];
    #pragma unroll
    for (int r = 0; r < 4; r++) { m[r] = -1e30f; lsum[r] = 0.f; }

    for (int kt = 0; kt < L_SEQ; kt += 64) {
        const int d = (kt >> 6) & 1;
        const int ktn = (kt + 64 < L_SEQ) ? kt + 64 : 0;  // tail: harmless
        asm volatile("s_waitcnt vmcnt(0)" ::: "memory");  // K(kt) landed
        __builtin_amdgcn_s_barrier();
        __builtin_amdgcn_sched_barrier(0);
        // stage V(kt) first (covered by vmcnt(4) below), then K(kt+1)
        #pragma unroll
        for (int j = 0; j < 4; j++) {
            const int rb = w * 32 + j * 8;
            const int row = rb + (lane >> 3);
            const int lc = (lane & 7) ^ (row & 7);
            gload_lds16(&Vp[(size_t)row * L_SEQ + kt + lc * 8], &Vts[rb * 64]);
        }
        #pragma unroll
        for (int j = 0; j < 4; j++) {
            const int rb = w * 16 + j * 4;
            const int row = rb + (lane >> 4);
            const int lc = (lane & 15) ^ (row & 7);
            gload_lds16(&Kp[(size_t)(ktn + row) * DH + lc * 8], &Ks[d ^ 1][rb * 128]);
        }

        // S = Q K^T  (rows: wave's 16 q; cols: 64 kv)
        f32x4 s[4] = {};
        __builtin_amdgcn_s_setprio(1);
        #pragma unroll
        for (int c = 0; c < 4; c++) {
            #pragma unroll
            for (int n = 0; n < 4; n++) {
                const int row = n * 16 + lr;
                const bf16x8 kf = *(const bf16x8*)
                    &Ks[d][row * 128 + (((c * 4 + quad) ^ (row & 7)) * 8)];
                s[n] = __builtin_amdgcn_mfma_f32_16x16x32_bf16(qf[c], kf, s[n], 0, 0, 0);
            }
        }
        __builtin_amdgcn_s_setprio(0);

        // online softmax (rows quad*4+r, spread over 16 lanes of the quad)
        float alpha[4];
        #pragma unroll
        for (int r = 0; r < 4; r++) {
            float t = fmaxf(fmaxf(s[0][r], s[1][r]), fmaxf(s[2][r], s[3][r]));
            t = fmaxf(t, __shfl_xor(t, 1));
            t = fmaxf(t, __shfl_xor(t, 2));
            t = fmaxf(t, __shfl_xor(t, 4));
            t = fmaxf(t, __shfl_xor(t, 8));
            const float mn = fmaxf(m[r], t);
            alpha[r] = __expf(m[r] - mn);
            m[r] = mn;
        }
        float psum[4] = {0.f, 0.f, 0.f, 0.f};
        #pragma unroll
        for (int n = 0; n < 4; n++) {
            #pragma unroll
            for (int r = 0; r < 4; r++) {
                const float p = __expf(s[n][r] - m[r]);
                psum[r] += p;
                Ps[w][quad * 4 + r][n * 16 + lr] = f2bf(p);
            }
        }
        #pragma unroll
        for (int r = 0; r < 4; r++) {
            float t = psum[r];
            t += __shfl_xor(t, 1); t += __shfl_xor(t, 2);
            t += __shfl_xor(t, 4); t += __shfl_xor(t, 8);
            lsum[r] = lsum[r] * alpha[r] + t;
        }
        #pragma unroll
        for (int dt = 0; dt < 8; dt++)
            #pragma unroll
            for (int r = 0; r < 4; r++) acc[dt][r] *= alpha[r];

        // V(kt) landed (oldest 4 loads); K(kt+1) may stay in flight
        asm volatile("s_waitcnt vmcnt(4)" ::: "memory");
        __builtin_amdgcn_s_barrier();
        __builtin_amdgcn_sched_barrier(0);

        // O += P V  (A = P from LDS, B = Vt rows)
        __builtin_amdgcn_s_setprio(1);
        #pragma unroll
        for (int jc = 0; jc < 2; jc++) {
            const bf16x8 pf = *(const bf16x8*)&Ps[w][lr][jc * 32 + quad * 8];
            #pragma unroll
            for (int dt = 0; dt < 8; dt++) {
                const int row = dt * 16 + lr;
                const bf16x8 vf = *(const bf16x8*)
                    &Vts[row * 64 + (((jc * 4 + quad) ^ (row & 7)) * 8)];
                acc[dt] = __builtin_amdgcn_mfma_f32_16x16x32_bf16(pf, vf, acc[dt], 0, 0, 0);
            }
        }
        __builtin_amdgcn_s_setprio(0);
    }

    float inv[4];
    #pragma unroll
    for (int r = 0; r < 4; r++) inv[r] = 1.f / lsum[r];
    unsigned short* orow = a2 + (size_t)(q0 + w * 16) * K2 + h * DH;
    #pragma unroll
    for (int dt = 0; dt < 8; dt++)
        #pragma unroll
        for (int r = 0; r < 4; r++)
            orow[(size_t)(quad * 4 + r) * K2 + dt * 16 + lr] = f2bf(acc[dt][r] * inv[r]);
}

// ---------------------------------------------------------------------------
extern "C" void kernel_launch(void* const* d_in, const int* in_sizes, int n_in,
                              void* d_out, int out_size, void* d_ws, size_t ws_size,
                              hipStream_t stream) {
    (void)in_sizes; (void)n_in; (void)out_size; (void)ws_size;
    const float* x      = (const float*)d_in[0];
    const float* vec    = (const float*)d_in[1];
    const float* pe     = (const float*)d_in[2];
    const float* mod_w  = (const float*)d_in[3];
    const float* mod_b  = (const float*)d_in[4];
    const float* gamma  = (const float*)d_in[5];
    const float* beta   = (const float*)d_in[6];
    const float* w1     = (const float*)d_in[7];
    const float* b1     = (const float*)d_in[8];
    const float* q_s    = (const float*)d_in[9];
    const float* k_s    = (const float*)d_in[10];
    const float* w2     = (const float*)d_in[11];
    const float* b2     = (const float*)d_in[12];
    float* out = (float*)d_out;

    char* ws = (char*)d_ws;
    size_t off = 0;
    float* modbuf = (float*)(ws + off);                  off += 40960;
    unsigned short* x_mod = (unsigned short*)(ws + off); off += (size_t)L_SEQ * HID * 2;
    float* qkv = (float*)(ws + off);                     off += (size_t)2 * NH * L_SEQ * DH * 4;
    unsigned short* qb  = (unsigned short*)(ws + off);   off += (size_t)NH * L_SEQ * DH * 2;
    unsigned short* kb  = (unsigned short*)(ws + off);   off += (size_t)NH * L_SEQ * DH * 2;
    unsigned short* vtb = (unsigned short*)(ws + off);   off += (size_t)NH * L_SEQ * DH * 2;
    unsigned short* a2  = (unsigned short*)(ws + off);   off += (size_t)L_SEQ * K2 * 2;
    unsigned short* w1t = (unsigned short*)(ws + off);   off += (size_t)N1 * HID * 2;
    unsigned short* w2t = (unsigned short*)(ws + off);   off += (size_t)HID * K2 * 2;
    // split-K partials alias qkv (dead after k_rmsrope): 2*2048*3072*4 bytes
    float* part = qkv;

    static bool s_init = false;
    if (!s_init) {
        s_init = true;
        hipFuncSetAttribute(reinterpret_cast<const void*>(&gemm8<0>),
                            hipFuncAttributeMaxDynamicSharedMemorySize, 131072);
        hipFuncSetAttribute(reinterpret_cast<const void*>(&gemm8<1>),
                            hipFuncAttributeMaxDynamicSharedMemorySize, 131072);
    }

    // weight convert+transpose (bf16, [N][K])
    k_convT<<<dim3(N1 / 64, HID / 64), 256, 0, stream>>>(w1, w1t, HID, N1);
    k_convT<<<dim3(HID / 64, K2 / 64), 256, 0, stream>>>(w2, w2t, K2, HID);

    hipMemsetAsync(modbuf, 0, 9216 * sizeof(float), stream);
    k_mod<<<dim3(36, 8), 256, 0, stream>>>(vec, mod_w, mod_b, modbuf);
    k_ln<<<L_SEQ, 256, 0, stream>>>(x, modbuf, gamma, beta, x_mod);

    gemm8<0><<<dim3(N1 / 256, L_SEQ / 256, 1), 512, 131072, stream>>>(
        x_mod, w1t, b1, HID, HID / 64, qkv, vtb, a2, nullptr);

    k_rmsrope<<<NH * L_SEQ, 64, 0, stream>>>(qkv, pe, q_s, k_s, qb, kb);
    attn_mfma<<<dim3(L_SEQ / 64, NH), 256, 0, stream>>>(qb, kb, vtb, a2);

    gemm8<1><<<dim3(HID / 256, L_SEQ / 256, 2), 512, 131072, stream>>>(
        a2, w2t, nullptr, K2, K2 / 2 / 64, nullptr, nullptr, nullptr, part);

    k_fin<<<dim3(HID / 1024, L_SEQ), 256, 0, stream>>>(part, x, modbuf, b2, out);
}